// Round 3
// baseline (271.685 us; speedup 1.0000x reference)
//
#include <hip/hip_runtime.h>

// EdgeLoss: mean |sobel_mag(gray(pred)) - sobel_mag(gray(target))|
// pred/target: (32, 3, 512, 512) fp32, output: scalar fp32.
// HBM floor: 201 MB read / 6.3 TB/s ~= 32 us.
//
// R2 -> R3: LDS-staging versions got register-minimized (VGPR 12/16) into
// dependent load chains -> 2.3 TB/s, latency-bound. New structure: no LDS,
// no barrier. Each thread owns a 4-wide strip, walks 16 rows, keeps 2 gray
// rows (6 floats x 2 imgs) rolling in registers. Per step: 18 independent
// float4 loads (16B-aligned), gray 6 cols, sobel 4 px. The rolling live
// ranges force real VGPR allocation and deep load pipelining.

#define BATCH 32
#define HH 512
#define WW 512
#define RR 16                 // rows per thread
#define BANDS 2
#define TILE_H (RR * BANDS)   // 32 rows per block

__global__ void zero_out_kernel(float* out) { out[0] = 0.0f; }

struct GRow { float v[6]; };   // gray cols x-1 .. x+4

__device__ __forceinline__ void zero_row(GRow& g) {
    #pragma unroll
    for (int i = 0; i < 6; ++i) g.v[i] = 0.0f;
}

__device__ __forceinline__ float grayf(float r, float g, float b) {
    return 0.299f * r + 0.587f * g + 0.114f * b;
}

// Load one source row (both images), convert to 6 gray columns each.
__device__ __forceinline__ void gray_row(
    const float* __restrict__ pbase, const float* __restrict__ tbase,
    int row, int x, bool okL, bool okR, GRow& gp, GRow& gt)
{
    const size_t img = (size_t)HH * WW;
    const float4 z4 = make_float4(0.f, 0.f, 0.f, 0.f);
    const float* pA = pbase + (size_t)row * WW + x;
    const float* tA = tbase + (size_t)row * WW + x;

    // Issue all 18 loads up front (independent, 16B-aligned).
    float4 prL = okL ? *(const float4*)(pA - 4)           : z4;
    float4 prM =       *(const float4*)(pA);
    float4 prR = okR ? *(const float4*)(pA + 4)           : z4;
    float4 pgL = okL ? *(const float4*)(pA + img - 4)     : z4;
    float4 pgM =       *(const float4*)(pA + img);
    float4 pgR = okR ? *(const float4*)(pA + img + 4)     : z4;
    float4 pbL = okL ? *(const float4*)(pA + 2 * img - 4) : z4;
    float4 pbM =       *(const float4*)(pA + 2 * img);
    float4 pbR = okR ? *(const float4*)(pA + 2 * img + 4) : z4;
    float4 trL = okL ? *(const float4*)(tA - 4)           : z4;
    float4 trM =       *(const float4*)(tA);
    float4 trR = okR ? *(const float4*)(tA + 4)           : z4;
    float4 tgL = okL ? *(const float4*)(tA + img - 4)     : z4;
    float4 tgM =       *(const float4*)(tA + img);
    float4 tgR = okR ? *(const float4*)(tA + img + 4)     : z4;
    float4 tbL = okL ? *(const float4*)(tA + 2 * img - 4) : z4;
    float4 tbM =       *(const float4*)(tA + 2 * img);
    float4 tbR = okR ? *(const float4*)(tA + 2 * img + 4) : z4;

    gp.v[0] = grayf(prL.w, pgL.w, pbL.w);
    gp.v[1] = grayf(prM.x, pgM.x, pbM.x);
    gp.v[2] = grayf(prM.y, pgM.y, pbM.y);
    gp.v[3] = grayf(prM.z, pgM.z, pbM.z);
    gp.v[4] = grayf(prM.w, pgM.w, pbM.w);
    gp.v[5] = grayf(prR.x, pgR.x, pbR.x);

    gt.v[0] = grayf(trL.w, tgL.w, tbL.w);
    gt.v[1] = grayf(trM.x, tgM.x, tbM.x);
    gt.v[2] = grayf(trM.y, tgM.y, tbM.y);
    gt.v[3] = grayf(trM.z, tgM.z, tbM.z);
    gt.v[4] = grayf(trM.w, tgM.w, tbM.w);
    gt.v[5] = grayf(trR.x, tgR.x, tbR.x);
}

// 4-px Sobel magnitude difference, rows (m1, c0, p1) = y-1, y, y+1.
__device__ __forceinline__ float sobel4(
    const GRow& pm1, const GRow& pc0, const GRow& pp1,
    const GRow& tm1, const GRow& tc0, const GRow& tp1)
{
    float s = 0.0f;
    #pragma unroll
    for (int i = 0; i < 4; ++i) {
        float ex = (pm1.v[i+2] - pm1.v[i]) + 2.0f * (pc0.v[i+2] - pc0.v[i])
                 + (pp1.v[i+2] - pp1.v[i]);
        float ey = (pp1.v[i] + 2.0f * pp1.v[i+1] + pp1.v[i+2])
                 - (pm1.v[i] + 2.0f * pm1.v[i+1] + pm1.v[i+2]);
        float ep = sqrtf(ex * ex + ey * ey);

        float fx = (tm1.v[i+2] - tm1.v[i]) + 2.0f * (tc0.v[i+2] - tc0.v[i])
                 + (tp1.v[i+2] - tp1.v[i]);
        float fy = (tp1.v[i] + 2.0f * tp1.v[i+1] + tp1.v[i+2])
                 - (tm1.v[i] + 2.0f * tm1.v[i+1] + tm1.v[i+2]);
        float et = sqrtf(fx * fx + fy * fy);

        s += fabsf(ep - et);
    }
    return s;
}

__global__ __launch_bounds__(256, 2) void edge_loss_kernel(
    const float* __restrict__ pred,
    const float* __restrict__ target,
    float* __restrict__ out)
{
    const int t    = threadIdx.x;
    const int tx   = t & 127;          // 0..127 -> x = 4*tx
    const int band = t >> 7;           // 0..1
    const int x    = tx * 4;
    const int b      = blockIdx.y;
    const int yStart = blockIdx.x * TILE_H + band * RR;

    const bool okL = (tx > 0);
    const bool okR = (tx < 127);

    const size_t img = (size_t)HH * WW;
    const float* pbase = pred   + (size_t)b * 3 * img;
    const float* tbase = target + (size_t)b * 3 * img;

    GRow pm1, pc0, tm1, tc0;
    if (yStart - 1 >= 0) gray_row(pbase, tbase, yStart - 1, x, okL, okR, pm1, tm1);
    else { zero_row(pm1); zero_row(tm1); }
    gray_row(pbase, tbase, yStart, x, okL, okR, pc0, tc0);

    float acc = 0.0f;
    #pragma unroll
    for (int k = 0; k < RR; ++k) {
        const int rnext = yStart + k + 1;
        GRow pp1, tp1;
        if (rnext < HH) gray_row(pbase, tbase, rnext, x, okL, okR, pp1, tp1);
        else { zero_row(pp1); zero_row(tp1); }

        acc += sobel4(pm1, pc0, pp1, tm1, tc0, tp1);

        pm1 = pc0; pc0 = pp1;
        tm1 = tc0; tc0 = tp1;
    }

    // ---- Reduce: wave shuffle -> cross-wave LDS -> one atomic per block ----
    #pragma unroll
    for (int off = 32; off > 0; off >>= 1)
        acc += __shfl_down(acc, off, 64);

    __shared__ float wsum[4];
    if ((t & 63) == 0) wsum[t >> 6] = acc;
    __syncthreads();
    if (t == 0) {
        const float s = wsum[0] + wsum[1] + wsum[2] + wsum[3];
        const float inv_n = 1.0f / ((float)BATCH * HH * WW);
        atomicAdd(out, s * inv_n);
    }
}

extern "C" void kernel_launch(void* const* d_in, const int* in_sizes, int n_in,
                              void* d_out, int out_size, void* d_ws, size_t ws_size,
                              hipStream_t stream) {
    const float* pred   = (const float*)d_in[0];
    const float* target = (const float*)d_in[1];
    float* out = (float*)d_out;

    // d_out is poisoned 0xAA before every timed launch -> zero it on-stream.
    zero_out_kernel<<<1, 1, 0, stream>>>(out);

    dim3 grid(HH / TILE_H, BATCH);  // (16, 32) = 512 blocks, 2 per CU
    edge_loss_kernel<<<grid, 256, 0, stream>>>(pred, target, out);
}

// Round 4
// 264.376 us; speedup vs baseline: 1.0276x; 1.0276x over previous
//
#include <hip/hip_runtime.h>

// EdgeLoss: mean |sobel_mag(gray(pred)) - sobel_mag(gray(target))|
// pred/target: (32, 3, 512, 512) fp32, output: scalar fp32.
// HBM floor: 201 MB read / 6.3 TB/s ~= 32 us.
//
// R3 -> R4: R3's rolling-register stencil spilled (18 loads/step, WRITE 18MB)
// and ran at 2 blocks/CU. Now: each thread loads ONLY its own 4 columns
// (6 float4/step, unconditional), border grays come from wave shuffles;
// lanes 0/63 patch via 6 scalar loads. RR=8, wave = 256x8 strip, block =
// 4 waves = 512x16 tile, grid (32,32) = 1024 blocks = 4/CU.

#define BATCH 32
#define HH 512
#define WW 512
#define RR 8                  // rows per wave strip
#define TILE_H (RR * 2)       // 16 rows per block (2 wave bands)

__global__ void zero_out_kernel(float* out) { out[0] = 0.0f; }

struct GRow { float v[6]; };   // gray cols x-1 .. x+4

__device__ __forceinline__ void zero_row(GRow& g) {
    #pragma unroll
    for (int i = 0; i < 6; ++i) g.v[i] = 0.0f;
}

__device__ __forceinline__ float grayf(float r, float g, float b) {
    return 0.299f * r + 0.587f * g + 0.114f * b;
}

// One source row: 6 own float4 loads, gray, shuffle borders, edge fixups.
__device__ __forceinline__ void gray_row(
    const float* __restrict__ pbase, const float* __restrict__ tbase,
    int row, int x, int lane, GRow& gp, GRow& gt)
{
    const size_t img = (size_t)HH * WW;
    const size_t o = (size_t)row * WW + x;

    const float4 pr = *(const float4*)(pbase + o);
    const float4 pg = *(const float4*)(pbase + o + img);
    const float4 pb = *(const float4*)(pbase + o + 2 * img);
    const float4 tr = *(const float4*)(tbase + o);
    const float4 tg = *(const float4*)(tbase + o + img);
    const float4 tb = *(const float4*)(tbase + o + 2 * img);

    const float p0 = grayf(pr.x, pg.x, pb.x);
    const float p1 = grayf(pr.y, pg.y, pb.y);
    const float p2 = grayf(pr.z, pg.z, pb.z);
    const float p3 = grayf(pr.w, pg.w, pb.w);
    const float t0 = grayf(tr.x, tg.x, tb.x);
    const float t1 = grayf(tr.y, tg.y, tb.y);
    const float t2 = grayf(tr.z, tg.z, tb.z);
    const float t3 = grayf(tr.w, tg.w, tb.w);

    // Border grays from neighbor lanes (cols x-1 and x+4).
    float pl = __shfl_up(p3, 1, 64);
    float pR = __shfl_down(p0, 1, 64);
    float tl = __shfl_up(t3, 1, 64);
    float tR = __shfl_down(t0, 1, 64);

    if (lane == 0) {
        if (x > 0) {  // col x-1 lives outside this wave's 256-wide strip
            pl = grayf(pbase[o - 1], pbase[o - 1 + img], pbase[o - 1 + 2 * img]);
            tl = grayf(tbase[o - 1], tbase[o - 1 + img], tbase[o - 1 + 2 * img]);
        } else { pl = 0.0f; tl = 0.0f; }
    }
    if (lane == 63) {
        if (x + 4 < WW) {
            pR = grayf(pbase[o + 4], pbase[o + 4 + img], pbase[o + 4 + 2 * img]);
            tR = grayf(tbase[o + 4], tbase[o + 4 + img], tbase[o + 4 + 2 * img]);
        } else { pR = 0.0f; tR = 0.0f; }
    }

    gp.v[0] = pl; gp.v[1] = p0; gp.v[2] = p1; gp.v[3] = p2; gp.v[4] = p3; gp.v[5] = pR;
    gt.v[0] = tl; gt.v[1] = t0; gt.v[2] = t1; gt.v[3] = t2; gt.v[4] = t3; gt.v[5] = tR;
}

// 4-px Sobel magnitude difference, rows (m1, c0, p1) = y-1, y, y+1.
__device__ __forceinline__ float sobel4(
    const GRow& pm1, const GRow& pc0, const GRow& pp1,
    const GRow& tm1, const GRow& tc0, const GRow& tp1)
{
    float s = 0.0f;
    #pragma unroll
    for (int i = 0; i < 4; ++i) {
        float ex = (pm1.v[i+2] - pm1.v[i]) + 2.0f * (pc0.v[i+2] - pc0.v[i])
                 + (pp1.v[i+2] - pp1.v[i]);
        float ey = (pp1.v[i] + 2.0f * pp1.v[i+1] + pp1.v[i+2])
                 - (pm1.v[i] + 2.0f * pm1.v[i+1] + pm1.v[i+2]);
        float ep = sqrtf(ex * ex + ey * ey);

        float fx = (tm1.v[i+2] - tm1.v[i]) + 2.0f * (tc0.v[i+2] - tc0.v[i])
                 + (tp1.v[i+2] - tp1.v[i]);
        float fy = (tp1.v[i] + 2.0f * tp1.v[i+1] + tp1.v[i+2])
                 - (tm1.v[i] + 2.0f * tm1.v[i+1] + tm1.v[i+2]);
        float et = sqrtf(fx * fx + fy * fy);

        s += fabsf(ep - et);
    }
    return s;
}

__global__ __launch_bounds__(256, 4) void edge_loss_kernel(
    const float* __restrict__ pred,
    const float* __restrict__ target,
    float* __restrict__ out)
{
    const int t    = threadIdx.x;
    const int lane = t & 63;
    const int wave = t >> 6;        // 0..3
    const int wx   = wave & 1;      // x half (0: cols 0-255, 1: 256-511)
    const int wy   = wave >> 1;     // y band within tile
    const int x    = wx * 256 + lane * 4;
    const int b      = blockIdx.y;
    const int yStart = blockIdx.x * TILE_H + wy * RR;

    const size_t img = (size_t)HH * WW;
    const float* pbase = pred   + (size_t)b * 3 * img;
    const float* tbase = target + (size_t)b * 3 * img;

    GRow pm1, pc0, tm1, tc0;
    if (yStart - 1 >= 0) gray_row(pbase, tbase, yStart - 1, x, lane, pm1, tm1);
    else { zero_row(pm1); zero_row(tm1); }
    gray_row(pbase, tbase, yStart, x, lane, pc0, tc0);

    float acc = 0.0f;
    #pragma unroll
    for (int k = 0; k < RR; ++k) {
        const int rnext = yStart + k + 1;
        GRow pp1, tp1;
        if (rnext < HH) gray_row(pbase, tbase, rnext, x, lane, pp1, tp1);
        else { zero_row(pp1); zero_row(tp1); }

        acc += sobel4(pm1, pc0, pp1, tm1, tc0, tp1);

        pm1 = pc0; pc0 = pp1;
        tm1 = tc0; tc0 = tp1;
    }

    // ---- Reduce: wave shuffle -> cross-wave LDS -> one atomic per block ----
    #pragma unroll
    for (int off = 32; off > 0; off >>= 1)
        acc += __shfl_down(acc, off, 64);

    __shared__ float wsum[4];
    if (lane == 0) wsum[wave] = acc;
    __syncthreads();
    if (t == 0) {
        const float s = wsum[0] + wsum[1] + wsum[2] + wsum[3];
        const float inv_n = 1.0f / ((float)BATCH * HH * WW);
        atomicAdd(out, s * inv_n);
    }
}

extern "C" void kernel_launch(void* const* d_in, const int* in_sizes, int n_in,
                              void* d_out, int out_size, void* d_ws, size_t ws_size,
                              hipStream_t stream) {
    const float* pred   = (const float*)d_in[0];
    const float* target = (const float*)d_in[1];
    float* out = (float*)d_out;

    // d_out is poisoned 0xAA before every timed launch -> zero it on-stream.
    zero_out_kernel<<<1, 1, 0, stream>>>(out);

    dim3 grid(HH / TILE_H, BATCH);  // (32, 32) = 1024 blocks, 4 per CU
    edge_loss_kernel<<<grid, 256, 0, stream>>>(pred, target, out);
}